// Round 2
// baseline (5546.451 us; speedup 1.0000x reference)
//
#include <hip/hip_runtime.h>
#include <cstdint>
#include <cstddef>

// Problem dims
#define B_ 16
#define L_ 2048
#define D_ 256
#define N_ 32
#define V_ 1024
#define M_ (B_ * L_)   // 32768 rows

typedef unsigned short u16;
typedef unsigned int   u32;
typedef __attribute__((ext_vector_type(8))) short bf16x8;   // 8 bf16 in 4 VGPRs (guide-verified form)
typedef __attribute__((ext_vector_type(4))) float f32x4;

// ---------- helpers ----------
__device__ inline u16 f2bf(float f) {
    u32 u = __builtin_bit_cast(u32, f);
    u32 r = (u + 0x7FFFu + ((u >> 16) & 1u)) >> 16;   // round-to-nearest-even
    return (u16)r;
}
__device__ inline float bf2f(u16 h) {
    u32 u = ((u32)h) << 16;
    return __builtin_bit_cast(float, u);
}
// jax.nn.gelu (approximate=True): 0.5x(1+tanh(c(x+0.044715x^3))) == x*sigmoid(2c(x+0.044715x^3))
__device__ inline float gelu_f(float x) {
    float t = 0.7978845608028654f * fmaf(0.044715f * x, x * x, x);
    return x / (1.f + __expf(-2.f * t));
}

// ---------- embedding gather: x[row,:] = emb[batch[row],:] ----------
__global__ __launch_bounds__(256) void embed_kernel(const int* __restrict__ batch,
                                                    const float* __restrict__ emb,
                                                    float* __restrict__ x) {
    const int row  = blockIdx.x * 4 + (threadIdx.x >> 6);
    const int lane = threadIdx.x & 63;
    const int tok  = batch[row];
    *(float4*)(x + (size_t)row * D_ + lane * 4) =
        *(const float4*)(emb + (size_t)tok * D_ + lane * 4);
}

// ---------- LayerNorm: one row (D=256) per 64-lane wave, 4 rows/block ----------
template<int OUTBF>
__global__ __launch_bounds__(256) void ln_kernel(const float* __restrict__ x,
                                                 const float* __restrict__ w,
                                                 const float* __restrict__ bias,
                                                 void* __restrict__ out) {
    const int row  = blockIdx.x * 4 + (threadIdx.x >> 6);
    const int lane = threadIdx.x & 63;
    const float4 v = *(const float4*)(x + (size_t)row * D_ + lane * 4);
    float s  = v.x + v.y + v.z + v.w;
    float ss = fmaf(v.x, v.x, fmaf(v.y, v.y, fmaf(v.z, v.z, v.w * v.w)));
#pragma unroll
    for (int m = 1; m < 64; m <<= 1) { s += __shfl_xor(s, m); ss += __shfl_xor(ss, m); }
    const float mu = s * (1.f / 256.f);
    const float rs = rsqrtf(ss * (1.f / 256.f) - mu * mu + 1e-5f);
    const float4 wv = *(const float4*)(w + lane * 4);
    const float4 bv = *(const float4*)(bias + lane * 4);
    const float o0 = (v.x - mu) * rs * wv.x + bv.x;
    const float o1 = (v.y - mu) * rs * wv.y + bv.y;
    const float o2 = (v.z - mu) * rs * wv.z + bv.z;
    const float o3 = (v.w - mu) * rs * wv.w + bv.w;
    if constexpr (OUTBF) {
        ushort4 p;
        p.x = f2bf(o0); p.y = f2bf(o1); p.z = f2bf(o2); p.w = f2bf(o3);
        *(ushort4*)((u16*)out + (size_t)row * D_ + lane * 4) = p;
    } else {
        float4 p; p.x = o0; p.y = o1; p.z = o2; p.w = o3;
        *(float4*)((float*)out + (size_t)row * D_ + lane * 4) = p;
    }
}

// ---------- weight prep: W[K,N] f32 -> Wt[N,K] bf16 (tiled transpose) ----------
__global__ __launch_bounds__(256) void wprep_kernel(const float* __restrict__ W,
                                                    u16* __restrict__ Wt, int K, int N) {
    __shared__ float t[32][33];
    const int k0 = blockIdx.y * 32, n0 = blockIdx.x * 32;
    const int r = threadIdx.x >> 5, c = threadIdx.x & 31;
#pragma unroll
    for (int i = 0; i < 32; i += 8) t[r + i][c] = W[(size_t)(k0 + r + i) * N + n0 + c];
    __syncthreads();
#pragma unroll
    for (int i = 0; i < 32; i += 8) Wt[(size_t)(n0 + r + i) * K + k0 + c] = f2bf(t[c][r + i]);
}

// ---------- S4D scan: per (b,d) group of 32 lanes, lane = state index n ----------
// y[b,l,d] = gelu( 2*Re(sum_n Cd_n * s_n[l]) + u[b,l,d]*Dsk[d] ),  s_n = w_n*s_n + u
__global__ __launch_bounds__(512) void scan_kernel(const float* __restrict__ u,
                                                   const float* __restrict__ log_dt,
                                                   const float* __restrict__ Alr,
                                                   const float* __restrict__ Aim,
                                                   const float* __restrict__ Cre,
                                                   const float* __restrict__ Cim,
                                                   const float* __restrict__ Dsk,
                                                   u16* __restrict__ y) {
    __shared__ float us[64][16];
    __shared__ u16   ys[64][16];
    const int b  = blockIdx.y;
    const int g  = threadIdx.x >> 5;   // d-slot within block: 0..15
    const int n  = threadIdx.x & 31;   // state index
    const int d  = blockIdx.x * 16 + g;
    const int dn = d * N_ + n;

    // discretization (per-lane, once)
    const float dt  = expf(log_dt[d]);
    const float are = -expf(Alr[dn]);
    const float aim = Aim[dn];
    const float zre = dt * are, zim = dt * aim;
    const float er  = expf(zre);
    float szim, czim;
    sincosf(zim, &szim, &czim);
    const float wre = er * czim, wim = er * szim;       // w = exp(dt*A)
    const float nre = wre - 1.f, nim = wim;             // exp(dtA) - 1
    const float ia  = 1.f / (are * are + aim * aim);
    const float tre = (nre * are + nim * aim) * ia;     // (exp(dtA)-1)/A
    const float tim = (nim * are - nre * aim) * ia;
    const float cr = Cre[dn], ci = Cim[dn];
    const float cdre = 2.f * (cr * tre - ci * tim);     // 2*Cd (fold the 2*Re factor)
    const float cdim = 2.f * (cr * tim + ci * tre);
    const float dsk = Dsk[d];

    const float* ub = u + (size_t)b * L_ * D_ + blockIdx.x * 16;
    u16*         yb = y + (size_t)b * L_ * D_ + blockIdx.x * 16;

    const int dd = threadIdx.x & 15, lq = threadIdx.x >> 4;  // u-stage map (512 thr -> 32 l x 16 d, x2)
    const int dp = threadIdx.x & 7,  lw = threadIdx.x >> 3;  // y-store map (512 thr -> 64 l x 8 pairs)

    float sre = 0.f, sim = 0.f;
    for (int l0 = 0; l0 < L_; l0 += 64) {
        us[lq][dd]      = ub[(size_t)(l0 + lq) * D_ + dd];
        us[lq + 32][dd] = ub[(size_t)(l0 + lq + 32) * D_ + dd];
        __syncthreads();
        for (int t = 0; t < 64; ++t) {
            const float uu = us[t][g];
            float a1 = fmaf(wre, sre, uu);
            a1 = fmaf(-wim, sim, a1);
            float a2 = wre * sim;
            a2 = fmaf(wim, sre, a2);
            sre = a1; sim = a2;
            float v = sre * cdre;
            v = fmaf(-cdim, sim, v);
            v += __shfl_xor(v, 1);
            v += __shfl_xor(v, 2);
            v += __shfl_xor(v, 4);
            v += __shfl_xor(v, 8);
            v += __shfl_xor(v, 16);
            if (n == 0) ys[t][g] = f2bf(gelu_f(fmaf(uu, dsk, v)));
        }
        __syncthreads();
        {
            const u32 lo = ys[lw][dp * 2], hi = ys[lw][dp * 2 + 1];
            *(u32*)(yb + (size_t)(l0 + lw) * D_ + dp * 2) = lo | (hi << 16);
        }
        __syncthreads();
    }
}

// ---------- bf16 MFMA GEMM, 128x128 tile, BK=32, 4 waves (each 64x64 = 4x4 frags) ----------
// A: bf16 [M,K] row-major. Bt: bf16 [N,K] row-major (weight pre-transposed).
// EPI 0: GLU  (paired strips n0 / n0+256 of Bt; x[row,col] += zl*sigmoid(zr))
// EPI 1: h[row,col] = bf16(gelu(acc+bias))
// EPI 2: x[row,col] += acc + bias
// EPI 3: out[row,col] = acc + bias (f32)
template<int EPI>
__global__ __launch_bounds__(256) void gemm_kernel(const u16* __restrict__ A,
                                                   const u16* __restrict__ Bt,
                                                   const float* __restrict__ bias,
                                                   float* __restrict__ xres,
                                                   u16* __restrict__ hout,
                                                   int K, int ldc) {
    constexpr int BR = (EPI == 0) ? 256 : 128;
    __shared__ __align__(16) u16 As[128][40];
    __shared__ __align__(16) u16 Bs[BR][40];
    const int m0 = blockIdx.x * 128;
    const int n0 = blockIdx.y * 128;
    const int tid = threadIdx.x;
    const int lane = tid & 63;
    const int wv = tid >> 6;
    const int wm = wv >> 1, wn = wv & 1;
    const int r = tid >> 2, q = (tid & 3) * 8;
    const int lrow = lane & 15, lk = (lane >> 4) * 8;

    f32x4 acc[4][4] = {};
    f32x4 acc2[(EPI == 0) ? 4 : 1][(EPI == 0) ? 4 : 1] = {};

    for (int k0 = 0; k0 < K; k0 += 32) {
        *(uint4*)&As[r][q]      = *(const uint4*)&A[(size_t)(m0 + r) * K + k0 + q];
        *(uint4*)&As[r + 64][q] = *(const uint4*)&A[(size_t)(m0 + r + 64) * K + k0 + q];
        *(uint4*)&Bs[r][q]      = *(const uint4*)&Bt[(size_t)(n0 + r) * K + k0 + q];
        *(uint4*)&Bs[r + 64][q] = *(const uint4*)&Bt[(size_t)(n0 + r + 64) * K + k0 + q];
        if constexpr (EPI == 0) {
            *(uint4*)&Bs[r + 128][q] = *(const uint4*)&Bt[(size_t)(n0 + 256 + r) * K + k0 + q];
            *(uint4*)&Bs[r + 192][q] = *(const uint4*)&Bt[(size_t)(n0 + 320 + r) * K + k0 + q];
        }
        __syncthreads();
        bf16x8 af[4], bfr[4], bf2[(EPI == 0) ? 4 : 1];
#pragma unroll
        for (int mf = 0; mf < 4; ++mf)
            af[mf] = *(const bf16x8*)&As[wm * 64 + mf * 16 + lrow][lk];
#pragma unroll
        for (int nf = 0; nf < 4; ++nf) {
            bfr[nf] = *(const bf16x8*)&Bs[wn * 64 + nf * 16 + lrow][lk];
            if constexpr (EPI == 0)
                bf2[nf] = *(const bf16x8*)&Bs[128 + wn * 64 + nf * 16 + lrow][lk];
        }
#pragma unroll
        for (int mf = 0; mf < 4; ++mf)
#pragma unroll
            for (int nf = 0; nf < 4; ++nf) {
                acc[mf][nf] = __builtin_amdgcn_mfma_f32_16x16x32_bf16(af[mf], bfr[nf], acc[mf][nf], 0, 0, 0);
                if constexpr (EPI == 0)
                    acc2[mf][nf] = __builtin_amdgcn_mfma_f32_16x16x32_bf16(af[mf], bf2[nf], acc2[mf][nf], 0, 0, 0);
            }
        __syncthreads();
    }

    // epilogue: D[row][col], col = lane&15, row = (lane>>4)*4 + j  (verified layout)
    const int rbase = m0 + wm * 64 + (lane >> 4) * 4;
    const int cbase = n0 + wn * 64 + (lane & 15);
#pragma unroll
    for (int mf = 0; mf < 4; ++mf)
#pragma unroll
        for (int nf = 0; nf < 4; ++nf)
#pragma unroll
            for (int j = 0; j < 4; ++j) {
                const int row = rbase + mf * 16 + j;
                const int col = cbase + nf * 16;
                const float a = acc[mf][nf][j];
                if constexpr (EPI == 0) {
                    const float zl = a + bias[col];
                    const float zr = acc2[mf][nf][j] + bias[col + 256];
                    xres[(size_t)row * ldc + col] += zl / (1.f + __expf(-zr));
                } else if constexpr (EPI == 1) {
                    hout[(size_t)row * ldc + col] = f2bf(gelu_f(a + bias[col]));
                } else if constexpr (EPI == 2) {
                    xres[(size_t)row * ldc + col] += a + bias[col];
                } else {
                    xres[(size_t)row * ldc + col] = a + bias[col];
                }
            }
}

// ---------- host launch ----------
extern "C" void kernel_launch(void* const* d_in, const int* in_sizes, int n_in,
                              void* d_out, int out_size, void* d_ws, size_t ws_size,
                              hipStream_t stream) {
    const int*   batch    = (const int*)  d_in[0];
    const float* emb      = (const float*)d_in[1];
    const float* s4_ln_w  = (const float*)d_in[2];
    const float* s4_ln_b  = (const float*)d_in[3];
    const float* s4_logdt = (const float*)d_in[4];
    const float* s4_Alr   = (const float*)d_in[5];
    const float* s4_Aim   = (const float*)d_in[6];
    const float* s4_Cre   = (const float*)d_in[7];
    const float* s4_Cim   = (const float*)d_in[8];
    const float* s4_D     = (const float*)d_in[9];
    const float* s4_Wout  = (const float*)d_in[10];
    const float* s4_bout  = (const float*)d_in[11];
    const float* ff_ln_w  = (const float*)d_in[12];
    const float* ff_ln_b  = (const float*)d_in[13];
    const float* ff_W1    = (const float*)d_in[14];
    const float* ff_b1    = (const float*)d_in[15];
    const float* ff_W2    = (const float*)d_in[16];
    const float* ff_b2    = (const float*)d_in[17];
    const float* fin_ln_w = (const float*)d_in[18];
    const float* fin_ln_b = (const float*)d_in[19];
    const float* W_vocab  = (const float*)d_in[20];
    const float* b_vocab  = (const float*)d_in[21];

    char* p = (char*)d_ws;
    float* x    = (float*)p; p += (size_t)M_ * D_ * 4;        // 33.5 MB residual stream (f32)
    float* uf   = (float*)p; p += (size_t)M_ * D_ * 4;        // 33.5 MB S4 LN out (f32)
    u16*   ubf  = (u16*)p;   p += (size_t)M_ * D_ * 2;        // 16.8 MB FF/final LN out (bf16)
    u16*   y    = (u16*)p;   p += (size_t)M_ * D_ * 2;        // 16.8 MB scan out (bf16)
    u16*   h    = (u16*)p;   p += (size_t)M_ * 4 * D_ * 2;    // 67 MB FF hidden (bf16)
    u16*   WoutT= (u16*)p;   p += (size_t)8 * 512 * 256 * 2;  // [512][256] x8
    u16*   W1T  = (u16*)p;   p += (size_t)4 * 1024 * 256 * 2; // [1024][256] x4
    u16*   W2T  = (u16*)p;   p += (size_t)4 * 256 * 1024 * 2; // [256][1024] x4
    u16*   WvT  = (u16*)p;   p += (size_t)1024 * 256 * 2;     // [1024][256]

    // ---- prep: embedding + weight transpose/convert ----
    embed_kernel<<<M_ / 4, 256, 0, stream>>>(batch, emb, x);
    for (int j = 0; j < 8; ++j)
        wprep_kernel<<<dim3(512 / 32, 256 / 32), 256, 0, stream>>>(
            s4_Wout + (size_t)j * 256 * 512, WoutT + (size_t)j * 512 * 256, 256, 512);
    for (int l = 0; l < 4; ++l)
        wprep_kernel<<<dim3(1024 / 32, 256 / 32), 256, 0, stream>>>(
            ff_W1 + (size_t)l * 256 * 1024, W1T + (size_t)l * 1024 * 256, 256, 1024);
    for (int l = 0; l < 4; ++l)
        wprep_kernel<<<dim3(256 / 32, 1024 / 32), 256, 0, stream>>>(
            ff_W2 + (size_t)l * 1024 * 256, W2T + (size_t)l * 256 * 1024, 1024, 256);
    wprep_kernel<<<dim3(1024 / 32, 256 / 32), 256, 0, stream>>>(W_vocab, WvT, 256, 1024);

    // ---- layers ----
    for (int lyr = 0; lyr < 4; ++lyr) {
        for (int jj = 0; jj < 2; ++jj) {
            const int j = 2 * lyr + jj;
            ln_kernel<0><<<M_ / 4, 256, 0, stream>>>(x, s4_ln_w + j * 256, s4_ln_b + j * 256, uf);
            scan_kernel<<<dim3(16, 16), 512, 0, stream>>>(
                uf, s4_logdt + j * 256,
                s4_Alr + (size_t)j * 8192, s4_Aim + (size_t)j * 8192,
                s4_Cre + (size_t)j * 8192, s4_Cim + (size_t)j * 8192,
                s4_D + j * 256, y);
            gemm_kernel<0><<<dim3(M_ / 128, 2), 256, 0, stream>>>(
                y, WoutT + (size_t)j * 512 * 256, s4_bout + j * 512, x, nullptr, 256, 256);
        }
        ln_kernel<1><<<M_ / 4, 256, 0, stream>>>(x, ff_ln_w + lyr * 256, ff_ln_b + lyr * 256, ubf);
        gemm_kernel<1><<<dim3(M_ / 128, 8), 256, 0, stream>>>(
            ubf, W1T + (size_t)lyr * 1024 * 256, ff_b1 + lyr * 1024, nullptr, h, 256, 1024);
        gemm_kernel<2><<<dim3(M_ / 128, 2), 256, 0, stream>>>(
            h, W2T + (size_t)lyr * 256 * 1024, ff_b2 + lyr * 256, x, nullptr, 1024, 256);
    }

    // ---- final LN + vocab projection ----
    ln_kernel<1><<<M_ / 4, 256, 0, stream>>>(x, fin_ln_w, fin_ln_b, ubf);
    gemm_kernel<3><<<dim3(M_ / 128, 8), 256, 0, stream>>>(
        ubf, WvT, b_vocab, (float*)d_out, nullptr, 256, 1024);
}

// Round 3
// 2040.516 us; speedup vs baseline: 2.7182x; 2.7182x over previous
//
#include <hip/hip_runtime.h>
#include <cstdint>
#include <cstddef>

// Problem dims
#define B_ 16
#define L_ 2048
#define D_ 256
#define N_ 32
#define V_ 1024
#define M_ (B_ * L_)   // 32768 rows

typedef unsigned short u16;
typedef unsigned int   u32;
typedef __attribute__((ext_vector_type(8))) short bf16x8;   // 8 bf16 in 4 VGPRs (guide-verified form)
typedef __attribute__((ext_vector_type(4))) float f32x4;

// ---------- helpers ----------
__device__ inline u16 f2bf(float f) {
    u32 u = __builtin_bit_cast(u32, f);
    u32 r = (u + 0x7FFFu + ((u >> 16) & 1u)) >> 16;   // round-to-nearest-even
    return (u16)r;
}
__device__ inline float bf2f(u16 h) {
    u32 u = ((u32)h) << 16;
    return __builtin_bit_cast(float, u);
}
// jax.nn.gelu (approximate=True): 0.5x(1+tanh(c(x+0.044715x^3))) == x*sigmoid(2c(x+0.044715x^3))
__device__ inline float gelu_f(float x) {
    float t = 0.7978845608028654f * fmaf(0.044715f * x, x * x, x);
    return x / (1.f + __expf(-2.f * t));
}
// sum over the lane's 16-lane DPP row via rotate-adds (pure VALU, no LDS)
template<int CTRL>
__device__ inline float dpp_add(float v) {
    int x = __builtin_bit_cast(int, v);
    int y = __builtin_amdgcn_update_dpp(x, x, CTRL, 0xF, 0xF, false);
    return v + __builtin_bit_cast(float, y);
}

// ---------- embedding gather: x[row,:] = emb[batch[row],:] ----------
__global__ __launch_bounds__(256) void embed_kernel(const int* __restrict__ batch,
                                                    const float* __restrict__ emb,
                                                    float* __restrict__ x) {
    const int row  = blockIdx.x * 4 + (threadIdx.x >> 6);
    const int lane = threadIdx.x & 63;
    const int tok  = batch[row];
    *(float4*)(x + (size_t)row * D_ + lane * 4) =
        *(const float4*)(emb + (size_t)tok * D_ + lane * 4);
}

// ---------- LayerNorm: one row (D=256) per 64-lane wave, 4 rows/block ----------
template<int OUTBF>
__global__ __launch_bounds__(256) void ln_kernel(const float* __restrict__ x,
                                                 const float* __restrict__ w,
                                                 const float* __restrict__ bias,
                                                 void* __restrict__ out) {
    const int row  = blockIdx.x * 4 + (threadIdx.x >> 6);
    const int lane = threadIdx.x & 63;
    const float4 v = *(const float4*)(x + (size_t)row * D_ + lane * 4);
    float s  = v.x + v.y + v.z + v.w;
    float ss = fmaf(v.x, v.x, fmaf(v.y, v.y, fmaf(v.z, v.z, v.w * v.w)));
#pragma unroll
    for (int m = 1; m < 64; m <<= 1) { s += __shfl_xor(s, m); ss += __shfl_xor(ss, m); }
    const float mu = s * (1.f / 256.f);
    const float rs = rsqrtf(ss * (1.f / 256.f) - mu * mu + 1e-5f);
    const float4 wv = *(const float4*)(w + lane * 4);
    const float4 bv = *(const float4*)(bias + lane * 4);
    const float o0 = (v.x - mu) * rs * wv.x + bv.x;
    const float o1 = (v.y - mu) * rs * wv.y + bv.y;
    const float o2 = (v.z - mu) * rs * wv.z + bv.z;
    const float o3 = (v.w - mu) * rs * wv.w + bv.w;
    if constexpr (OUTBF) {
        ushort4 p;
        p.x = f2bf(o0); p.y = f2bf(o1); p.z = f2bf(o2); p.w = f2bf(o3);
        *(ushort4*)((u16*)out + (size_t)row * D_ + lane * 4) = p;
    } else {
        float4 p; p.x = o0; p.y = o1; p.z = o2; p.w = o3;
        *(float4*)((float*)out + (size_t)row * D_ + lane * 4) = p;
    }
}

// ---------- weight prep: W[K,N] f32 -> Wt[N,K] bf16 (tiled transpose) ----------
__global__ __launch_bounds__(256) void wprep_kernel(const float* __restrict__ W,
                                                    u16* __restrict__ Wt, int K, int N) {
    __shared__ float t[32][33];
    const int k0 = blockIdx.y * 32, n0 = blockIdx.x * 32;
    const int r = threadIdx.x >> 5, c = threadIdx.x & 31;
#pragma unroll
    for (int i = 0; i < 32; i += 8) t[r + i][c] = W[(size_t)(k0 + r + i) * N + n0 + c];
    __syncthreads();
#pragma unroll
    for (int i = 0; i < 32; i += 8) Wt[(size_t)(n0 + r + i) * K + k0 + c] = f2bf(t[c][r + i]);
}

// ---------- S4D scan, DPP edition ----------
// 16 lanes per (b,d); lane q owns states n=q and n=q+16 (2 complex states).
// Per step: state update (8 FMA) + output dot (4) + row_ror reduce (4 DPP adds)
// + skip fma + cndmask collect. No LDS / shuffle on the recurrence path.
__global__ __launch_bounds__(256) void scan_kernel(const float* __restrict__ u,
                                                   const float* __restrict__ log_dt,
                                                   const float* __restrict__ Alr,
                                                   const float* __restrict__ Aim,
                                                   const float* __restrict__ Cre,
                                                   const float* __restrict__ Cim,
                                                   const float* __restrict__ Dsk,
                                                   u16* __restrict__ y) {
    __shared__ __align__(16) float us[16][68];   // [d][t] transposed, +4 pad
    __shared__ __align__(16) float ys[64][20];   // [t][d] raw pre-gelu, +4 pad
    const int b   = blockIdx.y;
    const int d0  = blockIdx.x * 16;
    const int tid = threadIdx.x;
    const int g   = tid >> 4;      // group (d offset), aligned to DPP rows
    const int q   = tid & 15;      // lane within group
    const int d   = d0 + g;

    // discretization for the two states (once)
    const float dt = expf(log_dt[d]);
    float wreA[2], wimA[2], creA[2], cimA[2];
#pragma unroll
    for (int s = 0; s < 2; ++s) {
        const int dn  = d * N_ + q + s * 16;
        const float are = -expf(Alr[dn]);
        const float aim = Aim[dn];
        const float er  = expf(dt * are);
        float sz, cz; sincosf(dt * aim, &sz, &cz);
        const float wr = er * cz, wi = er * sz;       // w = exp(dt*A)
        const float nr = wr - 1.f, ni = wi;
        const float ia = 1.f / (are * are + aim * aim);
        const float tr = (nr * are + ni * aim) * ia;  // (exp(dtA)-1)/A
        const float ti = (ni * are - nr * aim) * ia;
        const float cr = Cre[dn], ci = Cim[dn];
        wreA[s] = wr; wimA[s] = wi;
        creA[s] = 2.f * (cr * tr - ci * ti);          // 2*Cd
        cimA[s] = 2.f * (cr * ti + ci * tr);
    }
    const float dsk = Dsk[d];

    const float* ub = u + (size_t)b * L_ * D_;
    u16*         yb = y + (size_t)b * L_ * D_;

    const int sd = tid & 15, st4 = tid >> 4;   // staging map: d, t-quad
    const int srow = tid >> 2, sc4 = tid & 3;  // store map: t-row, d-quad

    float sre0 = 0.f, sim0 = 0.f, sre1 = 0.f, sim1 = 0.f;
    float ysel[4] = {0.f, 0.f, 0.f, 0.f};

    // prefetch tile 0 (4 scalar loads -> transposed LDS layout)
    float4 pv;
    pv.x = ub[(size_t)(st4 * 4 + 0) * D_ + d0 + sd];
    pv.y = ub[(size_t)(st4 * 4 + 1) * D_ + d0 + sd];
    pv.z = ub[(size_t)(st4 * 4 + 2) * D_ + d0 + sd];
    pv.w = ub[(size_t)(st4 * 4 + 3) * D_ + d0 + sd];

    for (int l0 = 0; l0 < L_; l0 += 64) {
        __syncthreads();                        // prev tile's us/ys fully consumed
        *(float4*)&us[sd][st4 * 4] = pv;
        __syncthreads();
        if (l0 + 64 < L_) {                     // prefetch next tile under compute
            const float* un = ub + (size_t)(l0 + 64) * D_;
            pv.x = un[(size_t)(st4 * 4 + 0) * D_ + d0 + sd];
            pv.y = un[(size_t)(st4 * 4 + 1) * D_ + d0 + sd];
            pv.z = un[(size_t)(st4 * 4 + 2) * D_ + d0 + sd];
            pv.w = un[(size_t)(st4 * 4 + 3) * D_ + d0 + sd];
        }
#pragma unroll
        for (int t8 = 0; t8 < 8; ++t8) {
            float uu8[8];
            *(float4*)&uu8[0] = *(const float4*)&us[g][t8 * 8];
            *(float4*)&uu8[4] = *(const float4*)&us[g][t8 * 8 + 4];
#pragma unroll
            for (int t1 = 0; t1 < 8; ++t1) {
                const int t = t8 * 8 + t1;
                const float uu = uu8[t1];
                float a0 = fmaf(wreA[0], sre0, uu); a0 = fmaf(-wimA[0], sim0, a0);
                float b0 = fmaf(wimA[0], sre0, wreA[0] * sim0);
                sre0 = a0; sim0 = b0;
                float a1 = fmaf(wreA[1], sre1, uu); a1 = fmaf(-wimA[1], sim1, a1);
                float b1 = fmaf(wimA[1], sre1, wreA[1] * sim1);
                sre1 = a1; sim1 = b1;
                float v = fmaf(creA[0], sre0,
                          fmaf(-cimA[0], sim0,
                          fmaf(creA[1], sre1, -cimA[1] * sim1)));
                v = dpp_add<0x121>(v);   // row_ror:1
                v = dpp_add<0x122>(v);   // row_ror:2
                v = dpp_add<0x124>(v);   // row_ror:4
                v = dpp_add<0x128>(v);   // row_ror:8  -> all 16 lanes hold the sum
                const float yv = fmaf(uu, dsk, v);
                ysel[t >> 4] = (q == (t & 15)) ? yv : ysel[t >> 4];
            }
        }
#pragma unroll
        for (int j = 0; j < 4; ++j) ys[j * 16 + q][g] = ysel[j];
        __syncthreads();
        {   // store phase: deferred gelu + bf16 pack, coalesced-ish 8B stores
            float4 vv = *(const float4*)&ys[srow][sc4 * 4];
            u32 p0 = (u32)f2bf(gelu_f(vv.x)) | ((u32)f2bf(gelu_f(vv.y)) << 16);
            u32 p1 = (u32)f2bf(gelu_f(vv.z)) | ((u32)f2bf(gelu_f(vv.w)) << 16);
            uint2 pk; pk.x = p0; pk.y = p1;
            *(uint2*)&yb[(size_t)(l0 + srow) * D_ + d0 + sc4 * 4] = pk;
        }
    }
}

// ---------- bf16 MFMA GEMM, 128x128 tile, BK=32, 4 waves (each 64x64 = 4x4 frags) ----------
// A: bf16 [M,K] row-major. Bt: bf16 [N,K] row-major (weight pre-transposed).
// EPI 0: GLU  (paired strips n0 / n0+256 of Bt; x[row,col] += zl*sigmoid(zr))
// EPI 1: h[row,col] = bf16(gelu(acc+bias))
// EPI 2: x[row,col] += acc + bias
// EPI 3: out[row,col] = acc + bias (f32)
template<int EPI>
__global__ __launch_bounds__(256) void gemm_kernel(const u16* __restrict__ A,
                                                   const u16* __restrict__ Bt,
                                                   const float* __restrict__ bias,
                                                   float* __restrict__ xres,
                                                   u16* __restrict__ hout,
                                                   int K, int ldc) {
    constexpr int BR = (EPI == 0) ? 256 : 128;
    __shared__ __align__(16) u16 As[128][40];
    __shared__ __align__(16) u16 Bs[BR][40];
    const int m0 = blockIdx.x * 128;
    const int n0 = blockIdx.y * 128;
    const int tid = threadIdx.x;
    const int lane = tid & 63;
    const int wv = tid >> 6;
    const int wm = wv >> 1, wn = wv & 1;
    const int r = tid >> 2, q = (tid & 3) * 8;
    const int lrow = lane & 15, lk = (lane >> 4) * 8;

    f32x4 acc[4][4] = {};
    f32x4 acc2[(EPI == 0) ? 4 : 1][(EPI == 0) ? 4 : 1] = {};

    for (int k0 = 0; k0 < K; k0 += 32) {
        *(uint4*)&As[r][q]      = *(const uint4*)&A[(size_t)(m0 + r) * K + k0 + q];
        *(uint4*)&As[r + 64][q] = *(const uint4*)&A[(size_t)(m0 + r + 64) * K + k0 + q];
        *(uint4*)&Bs[r][q]      = *(const uint4*)&Bt[(size_t)(n0 + r) * K + k0 + q];
        *(uint4*)&Bs[r + 64][q] = *(const uint4*)&Bt[(size_t)(n0 + r + 64) * K + k0 + q];
        if constexpr (EPI == 0) {
            *(uint4*)&Bs[r + 128][q] = *(const uint4*)&Bt[(size_t)(n0 + 256 + r) * K + k0 + q];
            *(uint4*)&Bs[r + 192][q] = *(const uint4*)&Bt[(size_t)(n0 + 320 + r) * K + k0 + q];
        }
        __syncthreads();
        bf16x8 af[4], bfr[4], bf2[(EPI == 0) ? 4 : 1];
#pragma unroll
        for (int mf = 0; mf < 4; ++mf)
            af[mf] = *(const bf16x8*)&As[wm * 64 + mf * 16 + lrow][lk];
#pragma unroll
        for (int nf = 0; nf < 4; ++nf) {
            bfr[nf] = *(const bf16x8*)&Bs[wn * 64 + nf * 16 + lrow][lk];
            if constexpr (EPI == 0)
                bf2[nf] = *(const bf16x8*)&Bs[128 + wn * 64 + nf * 16 + lrow][lk];
        }
#pragma unroll
        for (int mf = 0; mf < 4; ++mf)
#pragma unroll
            for (int nf = 0; nf < 4; ++nf) {
                acc[mf][nf] = __builtin_amdgcn_mfma_f32_16x16x32_bf16(af[mf], bfr[nf], acc[mf][nf], 0, 0, 0);
                if constexpr (EPI == 0)
                    acc2[mf][nf] = __builtin_amdgcn_mfma_f32_16x16x32_bf16(af[mf], bf2[nf], acc2[mf][nf], 0, 0, 0);
            }
        __syncthreads();
    }

    // epilogue: D[row][col], col = lane&15, row = (lane>>4)*4 + j  (verified layout)
    const int rbase = m0 + wm * 64 + (lane >> 4) * 4;
    const int cbase = n0 + wn * 64 + (lane & 15);
#pragma unroll
    for (int mf = 0; mf < 4; ++mf)
#pragma unroll
        for (int nf = 0; nf < 4; ++nf)
#pragma unroll
            for (int j = 0; j < 4; ++j) {
                const int row = rbase + mf * 16 + j;
                const int col = cbase + nf * 16;
                const float a = acc[mf][nf][j];
                if constexpr (EPI == 0) {
                    const float zl = a + bias[col];
                    const float zr = acc2[mf][nf][j] + bias[col + 256];
                    xres[(size_t)row * ldc + col] += zl / (1.f + __expf(-zr));
                } else if constexpr (EPI == 1) {
                    hout[(size_t)row * ldc + col] = f2bf(gelu_f(a + bias[col]));
                } else if constexpr (EPI == 2) {
                    xres[(size_t)row * ldc + col] += a + bias[col];
                } else {
                    xres[(size_t)row * ldc + col] = a + bias[col];
                }
            }
}

// ---------- host launch ----------
extern "C" void kernel_launch(void* const* d_in, const int* in_sizes, int n_in,
                              void* d_out, int out_size, void* d_ws, size_t ws_size,
                              hipStream_t stream) {
    const int*   batch    = (const int*)  d_in[0];
    const float* emb      = (const float*)d_in[1];
    const float* s4_ln_w  = (const float*)d_in[2];
    const float* s4_ln_b  = (const float*)d_in[3];
    const float* s4_logdt = (const float*)d_in[4];
    const float* s4_Alr   = (const float*)d_in[5];
    const float* s4_Aim   = (const float*)d_in[6];
    const float* s4_Cre   = (const float*)d_in[7];
    const float* s4_Cim   = (const float*)d_in[8];
    const float* s4_D     = (const float*)d_in[9];
    const float* s4_Wout  = (const float*)d_in[10];
    const float* s4_bout  = (const float*)d_in[11];
    const float* ff_ln_w  = (const float*)d_in[12];
    const float* ff_ln_b  = (const float*)d_in[13];
    const float* ff_W1    = (const float*)d_in[14];
    const float* ff_b1    = (const float*)d_in[15];
    const float* ff_W2    = (const float*)d_in[16];
    const float* ff_b2    = (const float*)d_in[17];
    const float* fin_ln_w = (const float*)d_in[18];
    const float* fin_ln_b = (const float*)d_in[19];
    const float* W_vocab  = (const float*)d_in[20];
    const float* b_vocab  = (const float*)d_in[21];

    char* p = (char*)d_ws;
    float* x    = (float*)p; p += (size_t)M_ * D_ * 4;        // 33.5 MB residual stream (f32)
    float* uf   = (float*)p; p += (size_t)M_ * D_ * 4;        // 33.5 MB S4 LN out (f32)
    u16*   ubf  = (u16*)p;   p += (size_t)M_ * D_ * 2;        // 16.8 MB FF/final LN out (bf16)
    u16*   y    = (u16*)p;   p += (size_t)M_ * D_ * 2;        // 16.8 MB scan out (bf16)
    u16*   h    = (u16*)p;   p += (size_t)M_ * 4 * D_ * 2;    // 67 MB FF hidden (bf16)
    u16*   WoutT= (u16*)p;   p += (size_t)8 * 512 * 256 * 2;  // [512][256] x8
    u16*   W1T  = (u16*)p;   p += (size_t)4 * 1024 * 256 * 2; // [1024][256] x4
    u16*   W2T  = (u16*)p;   p += (size_t)4 * 256 * 1024 * 2; // [256][1024] x4
    u16*   WvT  = (u16*)p;   p += (size_t)1024 * 256 * 2;     // [1024][256]

    // ---- prep: embedding + weight transpose/convert ----
    embed_kernel<<<M_ / 4, 256, 0, stream>>>(batch, emb, x);
    for (int j = 0; j < 8; ++j)
        wprep_kernel<<<dim3(512 / 32, 256 / 32), 256, 0, stream>>>(
            s4_Wout + (size_t)j * 256 * 512, WoutT + (size_t)j * 512 * 256, 256, 512);
    for (int l = 0; l < 4; ++l)
        wprep_kernel<<<dim3(1024 / 32, 256 / 32), 256, 0, stream>>>(
            ff_W1 + (size_t)l * 256 * 1024, W1T + (size_t)l * 1024 * 256, 256, 1024);
    for (int l = 0; l < 4; ++l)
        wprep_kernel<<<dim3(256 / 32, 1024 / 32), 256, 0, stream>>>(
            ff_W2 + (size_t)l * 1024 * 256, W2T + (size_t)l * 256 * 1024, 1024, 256);
    wprep_kernel<<<dim3(1024 / 32, 256 / 32), 256, 0, stream>>>(W_vocab, WvT, 256, 1024);

    // ---- layers ----
    for (int lyr = 0; lyr < 4; ++lyr) {
        for (int jj = 0; jj < 2; ++jj) {
            const int j = 2 * lyr + jj;
            ln_kernel<0><<<M_ / 4, 256, 0, stream>>>(x, s4_ln_w + j * 256, s4_ln_b + j * 256, uf);
            scan_kernel<<<dim3(16, 16), 256, 0, stream>>>(
                uf, s4_logdt + j * 256,
                s4_Alr + (size_t)j * 8192, s4_Aim + (size_t)j * 8192,
                s4_Cre + (size_t)j * 8192, s4_Cim + (size_t)j * 8192,
                s4_D + j * 256, y);
            gemm_kernel<0><<<dim3(M_ / 128, 2), 256, 0, stream>>>(
                y, WoutT + (size_t)j * 512 * 256, s4_bout + j * 512, x, nullptr, 256, 256);
        }
        ln_kernel<1><<<M_ / 4, 256, 0, stream>>>(x, ff_ln_w + lyr * 256, ff_ln_b + lyr * 256, ubf);
        gemm_kernel<1><<<dim3(M_ / 128, 8), 256, 0, stream>>>(
            ubf, W1T + (size_t)lyr * 1024 * 256, ff_b1 + lyr * 1024, nullptr, h, 256, 1024);
        gemm_kernel<2><<<dim3(M_ / 128, 2), 256, 0, stream>>>(
            h, W2T + (size_t)lyr * 256 * 1024, ff_b2 + lyr * 256, x, nullptr, 1024, 256);
    }

    // ---- final LN + vocab projection ----
    ln_kernel<1><<<M_ / 4, 256, 0, stream>>>(x, fin_ln_w, fin_ln_b, ubf);
    gemm_kernel<3><<<dim3(M_ / 128, 8), 256, 0, stream>>>(
        ubf, WvT, b_vocab, (float*)d_out, nullptr, 256, 1024);
}

// Round 4
// 1624.010 us; speedup vs baseline: 3.4153x; 1.2565x over previous
//
#include <hip/hip_runtime.h>
#include <cstdint>
#include <cstddef>

// Problem dims
#define B_ 16
#define L_ 2048
#define D_ 256
#define N_ 32
#define V_ 1024
#define M_ (B_ * L_)   // 32768 rows

typedef unsigned short u16;
typedef unsigned int   u32;
typedef __attribute__((ext_vector_type(8))) short bf16x8;
typedef __attribute__((ext_vector_type(4))) float f32x4;

// ---------- helpers ----------
__device__ inline u16 f2bf(float f) {
    u32 u = __builtin_bit_cast(u32, f);
    u32 r = (u + 0x7FFFu + ((u >> 16) & 1u)) >> 16;   // RNE
    return (u16)r;
}
__device__ inline float bf2f(u16 h) {
    u32 u = ((u32)h) << 16;
    return __builtin_bit_cast(float, u);
}
__device__ inline float gelu_f(float x) {
    float t = 0.7978845608028654f * fmaf(0.044715f * x, x * x, x);
    return x / (1.f + __expf(-2.f * t));
}

// ---------- embedding gather ----------
__global__ __launch_bounds__(256) void embed_kernel(const int* __restrict__ batch,
                                                    const float* __restrict__ emb,
                                                    float* __restrict__ x) {
    const int row  = blockIdx.x * 4 + (threadIdx.x >> 6);
    const int lane = threadIdx.x & 63;
    const int tok  = batch[row];
    *(float4*)(x + (size_t)row * D_ + lane * 4) =
        *(const float4*)(emb + (size_t)tok * D_ + lane * 4);
}

// ---------- LayerNorm ----------
template<int OUTBF>
__global__ __launch_bounds__(256) void ln_kernel(const float* __restrict__ x,
                                                 const float* __restrict__ w,
                                                 const float* __restrict__ bias,
                                                 void* __restrict__ out) {
    const int row  = blockIdx.x * 4 + (threadIdx.x >> 6);
    const int lane = threadIdx.x & 63;
    const float4 v = *(const float4*)(x + (size_t)row * D_ + lane * 4);
    float s  = v.x + v.y + v.z + v.w;
    float ss = fmaf(v.x, v.x, fmaf(v.y, v.y, fmaf(v.z, v.z, v.w * v.w)));
#pragma unroll
    for (int m = 1; m < 64; m <<= 1) { s += __shfl_xor(s, m); ss += __shfl_xor(ss, m); }
    const float mu = s * (1.f / 256.f);
    const float rs = rsqrtf(ss * (1.f / 256.f) - mu * mu + 1e-5f);
    const float4 wv = *(const float4*)(w + lane * 4);
    const float4 bv = *(const float4*)(bias + lane * 4);
    const float o0 = (v.x - mu) * rs * wv.x + bv.x;
    const float o1 = (v.y - mu) * rs * wv.y + bv.y;
    const float o2 = (v.z - mu) * rs * wv.z + bv.z;
    const float o3 = (v.w - mu) * rs * wv.w + bv.w;
    if constexpr (OUTBF) {
        ushort4 p;
        p.x = f2bf(o0); p.y = f2bf(o1); p.z = f2bf(o2); p.w = f2bf(o3);
        *(ushort4*)((u16*)out + (size_t)row * D_ + lane * 4) = p;
    } else {
        float4 p; p.x = o0; p.y = o1; p.z = o2; p.w = o3;
        *(float4*)((float*)out + (size_t)row * D_ + lane * 4) = p;
    }
}

// ---------- weight prep: W[K,N] f32 -> Wt[N,K] bf16 ----------
__global__ __launch_bounds__(256) void wprep_kernel(const float* __restrict__ W,
                                                    u16* __restrict__ Wt, int K, int N) {
    __shared__ float t[32][33];
    const int k0 = blockIdx.y * 32, n0 = blockIdx.x * 32;
    const int r = threadIdx.x >> 5, c = threadIdx.x & 31;
#pragma unroll
    for (int i = 0; i < 32; i += 8) t[r + i][c] = W[(size_t)(k0 + r + i) * N + n0 + c];
    __syncthreads();
#pragma unroll
    for (int i = 0; i < 32; i += 8) Wt[(size_t)(n0 + r + i) * K + k0 + c] = f2bf(t[c][r + i]);
}

// ---------- generic u16 transpose: src[R][C] -> dst[C][R], 64x64 tiles ----------
// grid (C/64, R/64), 256 threads
__global__ __launch_bounds__(256) void transpose_u16(const u16* __restrict__ src,
                                                     u16* __restrict__ dst, int R, int C) {
    __shared__ u16 tl[64][68];
    const int c0 = blockIdx.x * 64, r0 = blockIdx.y * 64;
    const int t = threadIdx.x;
    const int rr = t >> 2, cq = (t & 3) * 16;
    *(uint4*)&tl[rr][cq]     = *(const uint4*)&src[(size_t)(r0 + rr) * C + c0 + cq];
    *(uint4*)&tl[rr][cq + 8] = *(const uint4*)&src[(size_t)(r0 + rr) * C + c0 + cq + 8];
    __syncthreads();
    u16 tmp[16];
#pragma unroll
    for (int i = 0; i < 16; ++i) tmp[i] = tl[cq + i][rr];
    *(uint4*)&dst[(size_t)(c0 + rr) * R + r0 + cq]     = *(uint4*)&tmp[0];
    *(uint4*)&dst[(size_t)(c0 + rr) * R + r0 + cq + 8] = *(uint4*)&tmp[8];
}

// ---------- pk: per-d scan matrices (Tk|Vc stacked cols, G) ----------
// TkVc[d][64 r][128]: cols 0..63 Tk (skip on diag), cols 64..127 Vc
// GB[d][64 n2][64 r]
__global__ __launch_bounds__(256) void pk_kernel(const float* __restrict__ log_dt,
                                                 const float* __restrict__ Alr,
                                                 const float* __restrict__ Aim,
                                                 const float* __restrict__ Cre,
                                                 const float* __restrict__ Cim,
                                                 const float* __restrict__ Dsk,
                                                 u16* __restrict__ GB,
                                                 u16* __restrict__ TkVc) {
    __shared__ float wre[65][32], wim[65][32], c2re[32], c2im[32], Kv[64];
    const int d = blockIdx.x;
    const int tid = threadIdx.x;
    const float dt = expf(log_dt[d]);
    for (int e = tid; e < 65 * 32; e += 256) {
        const int m = e >> 5, n = e & 31;
        const float are = -expf(Alr[d * 32 + n]);
        const float aim = Aim[d * 32 + n];
        const float mag = expf((float)m * dt * are);
        float sz, cz; sincosf((float)m * dt * aim, &sz, &cz);
        wre[m][n] = mag * cz; wim[m][n] = mag * sz;
    }
    if (tid < 32) {
        const int n = tid;
        const float are = -expf(Alr[d * 32 + n]);
        const float aim = Aim[d * 32 + n];
        const float er = expf(dt * are);
        float sz, cz; sincosf(dt * aim, &sz, &cz);
        const float wr = er * cz, wi = er * sz;
        const float nr = wr - 1.f, ni = wi;
        const float ia = 1.f / (are * are + aim * aim);
        const float tr = (nr * are + ni * aim) * ia;
        const float ti = (ni * are - nr * aim) * ia;
        const float cr = Cre[d * 32 + n], ci = Cim[d * 32 + n];
        c2re[n] = 2.f * (cr * tr - ci * ti);
        c2im[n] = 2.f * (cr * ti + ci * tr);
    }
    __syncthreads();
    if (tid < 64) {
        float acc = 0.f;
#pragma unroll
        for (int n = 0; n < 32; ++n)
            acc += c2re[n] * wre[tid][n] - c2im[n] * wim[tid][n];
        Kv[tid] = acc;
    }
    __syncthreads();
    const float dsk = Dsk[d];
    for (int e = tid; e < 8192; e += 256) {
        const int r = e >> 7, cc = e & 127;
        float v;
        if (cc < 64) {
            v = (r > cc) ? Kv[r - cc] : ((r == cc) ? Kv[0] + dsk : 0.f);
        } else {
            const int n2 = cc - 64, n = n2 >> 1, m = r + 1;
            const float qre = c2re[n] * wre[m][n] - c2im[n] * wim[m][n];
            const float qim = c2re[n] * wim[m][n] + c2im[n] * wre[m][n];
            v = (n2 & 1) ? -qim : qre;
        }
        TkVc[(size_t)d * 8192 + e] = f2bf(v);
    }
    for (int e = tid; e < 4096; e += 256) {
        const int n2 = e >> 6, r = e & 63, n = n2 >> 1, m = 63 - r;
        GB[(size_t)d * 4096 + e] = f2bf((n2 & 1) ? wim[m][n] : wre[m][n]);
    }
}

// ---------- kstate: Sloc[d][b][n2][c] = G @ U  (chunk-end local states) ----------
// grid (4 bct, 256 d), 128 threads (2 waves)
__global__ __launch_bounds__(128) void kstate_kernel(const u16* __restrict__ GB,
                                                     const u16* __restrict__ uT,
                                                     float* __restrict__ Sloc) {
    __shared__ __align__(16) u16 As[64][72];
    __shared__ __align__(16) u16 Bs[128][72];
    const int d = blockIdx.y, bct = blockIdx.x;
    const int tid = threadIdx.x;
#pragma unroll
    for (int i = 0; i < 4; ++i) {
        const int e = tid * 8 + i * 1024;
        *(uint4*)&As[e >> 6][e & 63] = *(const uint4*)&GB[(size_t)d * 4096 + e];
    }
#pragma unroll
    for (int i = 0; i < 8; ++i) {
        const int e = tid * 8 + i * 1024;
        *(uint4*)&Bs[e >> 6][e & 63] = *(const uint4*)&uT[(size_t)d * 32768 + bct * 8192 + e];
    }
    __syncthreads();
    const int lane = tid & 63, wv = tid >> 6;
    const int lrow = lane & 15, lk = (lane >> 4) * 8;
    f32x4 acc[4][4] = {};
#pragma unroll
    for (int ks = 0; ks < 2; ++ks) {
        bf16x8 af[4], bfr[4];
#pragma unroll
        for (int mf = 0; mf < 4; ++mf) af[mf] = *(const bf16x8*)&As[mf * 16 + lrow][ks * 32 + lk];
#pragma unroll
        for (int nf = 0; nf < 4; ++nf) bfr[nf] = *(const bf16x8*)&Bs[wv * 64 + nf * 16 + lrow][ks * 32 + lk];
#pragma unroll
        for (int mf = 0; mf < 4; ++mf)
#pragma unroll
            for (int nf = 0; nf < 4; ++nf)
                acc[mf][nf] = __builtin_amdgcn_mfma_f32_16x16x32_bf16(af[mf], bfr[nf], acc[mf][nf], 0, 0, 0);
    }
    const int rbase = (lane >> 4) * 4;
#pragma unroll
    for (int mf = 0; mf < 4; ++mf)
#pragma unroll
        for (int nf = 0; nf < 4; ++nf)
#pragma unroll
            for (int j = 0; j < 4; ++j) {
                const int n2 = rbase + mf * 16 + j;
                const int bc_g = bct * 128 + wv * 64 + nf * 16 + (lane & 15);
                Sloc[((size_t)(d * 16 + (bc_g >> 5)) * 64 + n2) * 32 + (bc_g & 31)] = acc[mf][nf][j];
            }
}

// ---------- kcross: carry scan + y = gelu(Tk@U + Vc@Carry), store yT ----------
// grid (4 bct, 256 d), 128 threads (2 waves)
__global__ __launch_bounds__(128) void kcross_kernel(const u16* __restrict__ TkVc,
                                                     const u16* __restrict__ uT,
                                                     const float* __restrict__ Sloc,
                                                     const float* __restrict__ log_dt,
                                                     const float* __restrict__ Alr,
                                                     const float* __restrict__ Aim,
                                                     u16* __restrict__ yT) {
    __shared__ __align__(16) u16 As[64][136];
    __shared__ __align__(16) u16 Bs[128][136];
    __shared__ u16 ys[64][132];
    const int d = blockIdx.y, bct = blockIdx.x;
    const int tid = threadIdx.x;
    // stage A = [Tk | Vc] (64 x 128)
#pragma unroll
    for (int i = 0; i < 8; ++i) {
        const int e = tid * 8 + i * 1024;
        *(uint4*)&As[e >> 7][e & 127] = *(const uint4*)&TkVc[(size_t)d * 8192 + e];
    }
    // stage B cols 0..63 = U tile (128 bc x 64 r)
#pragma unroll
    for (int i = 0; i < 8; ++i) {
        const int e = tid * 8 + i * 1024;
        *(uint4*)&Bs[e >> 6][e & 63] = *(const uint4*)&uT[(size_t)d * 32768 + bct * 8192 + e];
    }
    // carry scan -> B cols 64..127 (bf16), thread = (b_local, n)
    {
        const int b_l = tid >> 5, n = tid & 31;
        const int b_g = bct * 4 + b_l;
        const float dt = expf(log_dt[d]);
        const float are = -expf(Alr[d * 32 + n]);
        const float aim = Aim[d * 32 + n];
        const float er = expf(dt * are);
        float sz, cz; sincosf(dt * aim, &sz, &cz);
        float wr = er * cz, wi = er * sz;        // w
#pragma unroll
        for (int sq = 0; sq < 6; ++sq) {          // w^64
            const float nr = wr * wr - wi * wi;
            wi = 2.f * wr * wi; wr = nr;
        }
        const float* Sp = Sloc + (size_t)(d * 16 + b_g) * 64 * 32;
        float cre = 0.f, cim = 0.f;
#pragma unroll
        for (int c = 0; c < 32; ++c) {
            Bs[b_l * 32 + c][64 + 2 * n]     = f2bf(cre);
            Bs[b_l * 32 + c][64 + 2 * n + 1] = f2bf(cim);
            const float sre = Sp[(2 * n) * 32 + c];
            const float sim = Sp[(2 * n + 1) * 32 + c];
            const float t0 = fmaf(wr, cre, fmaf(-wi, cim, sre));
            cim = fmaf(wr, cim, fmaf(wi, cre, sim));
            cre = t0;
        }
    }
    __syncthreads();
    const int lane = tid & 63, wv = tid >> 6;
    const int lrow = lane & 15, lk = (lane >> 4) * 8;
    f32x4 acc[4][4] = {};
#pragma unroll
    for (int ks = 0; ks < 4; ++ks) {
        bf16x8 af[4], bfr[4];
#pragma unroll
        for (int mf = 0; mf < 4; ++mf) af[mf] = *(const bf16x8*)&As[mf * 16 + lrow][ks * 32 + lk];
#pragma unroll
        for (int nf = 0; nf < 4; ++nf) bfr[nf] = *(const bf16x8*)&Bs[wv * 64 + nf * 16 + lrow][ks * 32 + lk];
#pragma unroll
        for (int mf = 0; mf < 4; ++mf)
#pragma unroll
            for (int nf = 0; nf < 4; ++nf)
                acc[mf][nf] = __builtin_amdgcn_mfma_f32_16x16x32_bf16(af[mf], bfr[nf], acc[mf][nf], 0, 0, 0);
    }
    const int rbase = (lane >> 4) * 4;
#pragma unroll
    for (int mf = 0; mf < 4; ++mf)
#pragma unroll
        for (int nf = 0; nf < 4; ++nf)
#pragma unroll
            for (int j = 0; j < 4; ++j) {
                const int r = rbase + mf * 16 + j;
                const int col = wv * 64 + nf * 16 + (lane & 15);
                ys[r][col] = f2bf(gelu_f(acc[mf][nf][j]));
            }
    __syncthreads();
    // coalesced store: thread owns one bc column (64 r contiguous in yT)
#pragma unroll
    for (int i = 0; i < 8; ++i) {
        u16 tmp[8];
#pragma unroll
        for (int k = 0; k < 8; ++k) tmp[k] = ys[i * 8 + k][tid];
        *(uint4*)&yT[(size_t)d * 32768 + (size_t)(bct * 128 + tid) * 64 + i * 8] = *(uint4*)&tmp[0];
    }
}

// ---------- bf16 MFMA GEMM (unchanged, verified) ----------
template<int EPI>
__global__ __launch_bounds__(256) void gemm_kernel(const u16* __restrict__ A,
                                                   const u16* __restrict__ Bt,
                                                   const float* __restrict__ bias,
                                                   float* __restrict__ xres,
                                                   u16* __restrict__ hout,
                                                   int K, int ldc) {
    constexpr int BR = (EPI == 0) ? 256 : 128;
    __shared__ __align__(16) u16 As[128][40];
    __shared__ __align__(16) u16 Bs[BR][40];
    const int m0 = blockIdx.x * 128;
    const int n0 = blockIdx.y * 128;
    const int tid = threadIdx.x;
    const int lane = tid & 63;
    const int wv = tid >> 6;
    const int wm = wv >> 1, wn = wv & 1;
    const int r = tid >> 2, q = (tid & 3) * 8;
    const int lrow = lane & 15, lk = (lane >> 4) * 8;

    f32x4 acc[4][4] = {};
    f32x4 acc2[(EPI == 0) ? 4 : 1][(EPI == 0) ? 4 : 1] = {};

    for (int k0 = 0; k0 < K; k0 += 32) {
        *(uint4*)&As[r][q]      = *(const uint4*)&A[(size_t)(m0 + r) * K + k0 + q];
        *(uint4*)&As[r + 64][q] = *(const uint4*)&A[(size_t)(m0 + r + 64) * K + k0 + q];
        *(uint4*)&Bs[r][q]      = *(const uint4*)&Bt[(size_t)(n0 + r) * K + k0 + q];
        *(uint4*)&Bs[r + 64][q] = *(const uint4*)&Bt[(size_t)(n0 + r + 64) * K + k0 + q];
        if constexpr (EPI == 0) {
            *(uint4*)&Bs[r + 128][q] = *(const uint4*)&Bt[(size_t)(n0 + 256 + r) * K + k0 + q];
            *(uint4*)&Bs[r + 192][q] = *(const uint4*)&Bt[(size_t)(n0 + 320 + r) * K + k0 + q];
        }
        __syncthreads();
        bf16x8 af[4], bfr[4], bf2[(EPI == 0) ? 4 : 1];
#pragma unroll
        for (int mf = 0; mf < 4; ++mf)
            af[mf] = *(const bf16x8*)&As[wm * 64 + mf * 16 + lrow][lk];
#pragma unroll
        for (int nf = 0; nf < 4; ++nf) {
            bfr[nf] = *(const bf16x8*)&Bs[wn * 64 + nf * 16 + lrow][lk];
            if constexpr (EPI == 0)
                bf2[nf] = *(const bf16x8*)&Bs[128 + wn * 64 + nf * 16 + lrow][lk];
        }
#pragma unroll
        for (int mf = 0; mf < 4; ++mf)
#pragma unroll
            for (int nf = 0; nf < 4; ++nf) {
                acc[mf][nf] = __builtin_amdgcn_mfma_f32_16x16x32_bf16(af[mf], bfr[nf], acc[mf][nf], 0, 0, 0);
                if constexpr (EPI == 0)
                    acc2[mf][nf] = __builtin_amdgcn_mfma_f32_16x16x32_bf16(af[mf], bf2[nf], acc2[mf][nf], 0, 0, 0);
            }
        __syncthreads();
    }

    const int rbase = m0 + wm * 64 + (lane >> 4) * 4;
    const int cbase = n0 + wn * 64 + (lane & 15);
#pragma unroll
    for (int mf = 0; mf < 4; ++mf)
#pragma unroll
        for (int nf = 0; nf < 4; ++nf)
#pragma unroll
            for (int j = 0; j < 4; ++j) {
                const int row = rbase + mf * 16 + j;
                const int col = cbase + nf * 16;
                const float a = acc[mf][nf][j];
                if constexpr (EPI == 0) {
                    const float zl = a + bias[col];
                    const float zr = acc2[mf][nf][j] + bias[col + 256];
                    xres[(size_t)row * ldc + col] += zl / (1.f + __expf(-zr));
                } else if constexpr (EPI == 1) {
                    hout[(size_t)row * ldc + col] = f2bf(gelu_f(a + bias[col]));
                } else if constexpr (EPI == 2) {
                    xres[(size_t)row * ldc + col] += a + bias[col];
                } else {
                    xres[(size_t)row * ldc + col] = a + bias[col];
                }
            }
}

// ---------- host launch ----------
extern "C" void kernel_launch(void* const* d_in, const int* in_sizes, int n_in,
                              void* d_out, int out_size, void* d_ws, size_t ws_size,
                              hipStream_t stream) {
    const int*   batch    = (const int*)  d_in[0];
    const float* emb      = (const float*)d_in[1];
    const float* s4_ln_w  = (const float*)d_in[2];
    const float* s4_ln_b  = (const float*)d_in[3];
    const float* s4_logdt = (const float*)d_in[4];
    const float* s4_Alr   = (const float*)d_in[5];
    const float* s4_Aim   = (const float*)d_in[6];
    const float* s4_Cre   = (const float*)d_in[7];
    const float* s4_Cim   = (const float*)d_in[8];
    const float* s4_D     = (const float*)d_in[9];
    const float* s4_Wout  = (const float*)d_in[10];
    const float* s4_bout  = (const float*)d_in[11];
    const float* ff_ln_w  = (const float*)d_in[12];
    const float* ff_ln_b  = (const float*)d_in[13];
    const float* ff_W1    = (const float*)d_in[14];
    const float* ff_b1    = (const float*)d_in[15];
    const float* ff_W2    = (const float*)d_in[16];
    const float* ff_b2    = (const float*)d_in[17];
    const float* fin_ln_w = (const float*)d_in[18];
    const float* fin_ln_b = (const float*)d_in[19];
    const float* W_vocab  = (const float*)d_in[20];
    const float* b_vocab  = (const float*)d_in[21];

    char* p = (char*)d_ws;
    float* x    = (float*)p; p += (size_t)M_ * D_ * 4;        // 33.5 MB residual (f32)
    u16*   ubf  = (u16*)p;   p += (size_t)M_ * D_ * 2;        // 16.8 MB LN out (bf16)
    u16*   uT   = (u16*)p;   p += (size_t)M_ * D_ * 2;        // 16.8 MB u d-major
    u16*   y    = (u16*)p;   p += (size_t)M_ * D_ * 2;        // 16.8 MB scan out (bl-major)
    u16*   yT   = (u16*)p;   p += (size_t)M_ * D_ * 2;        // 16.8 MB scan out d-major
    char*  big  = p;         p += (size_t)M_ * 4 * D_ * 2;    // 67 MB: h (FF) | Sloc (scan)
    u16*   h    = (u16*)big;
    float* Sloc = (float*)big;                                // [256][16][64][32] f32 = 33.5 MB
    u16*   GB   = (u16*)p;   p += (size_t)256 * 4096 * 2;     // 2.1 MB
    u16*   TkVc = (u16*)p;   p += (size_t)256 * 8192 * 2;     // 4.2 MB
    u16*   WoutT= (u16*)p;   p += (size_t)8 * 512 * 256 * 2;
    u16*   W1T  = (u16*)p;   p += (size_t)4 * 1024 * 256 * 2;
    u16*   W2T  = (u16*)p;   p += (size_t)4 * 256 * 1024 * 2;
    u16*   WvT  = (u16*)p;   p += (size_t)1024 * 256 * 2;

    // ---- prep ----
    embed_kernel<<<M_ / 4, 256, 0, stream>>>(batch, emb, x);
    for (int j = 0; j < 8; ++j)
        wprep_kernel<<<dim3(512 / 32, 256 / 32), 256, 0, stream>>>(
            s4_Wout + (size_t)j * 256 * 512, WoutT + (size_t)j * 512 * 256, 256, 512);
    for (int l = 0; l < 4; ++l)
        wprep_kernel<<<dim3(1024 / 32, 256 / 32), 256, 0, stream>>>(
            ff_W1 + (size_t)l * 256 * 1024, W1T + (size_t)l * 1024 * 256, 256, 1024);
    for (int l = 0; l < 4; ++l)
        wprep_kernel<<<dim3(256 / 32, 1024 / 32), 256, 0, stream>>>(
            ff_W2 + (size_t)l * 1024 * 256, W2T + (size_t)l * 256 * 1024, 1024, 256);
    wprep_kernel<<<dim3(1024 / 32, 256 / 32), 256, 0, stream>>>(W_vocab, WvT, 256, 1024);

    // ---- layers ----
    for (int lyr = 0; lyr < 4; ++lyr) {
        for (int jj = 0; jj < 2; ++jj) {
            const int j = 2 * lyr + jj;
            ln_kernel<1><<<M_ / 4, 256, 0, stream>>>(x, s4_ln_w + j * 256, s4_ln_b + j * 256, ubf);
            transpose_u16<<<dim3(4, 512), 256, 0, stream>>>(ubf, uT, M_, D_);
            pk_kernel<<<256, 256, 0, stream>>>(
                s4_logdt + j * 256,
                s4_Alr + (size_t)j * 8192, s4_Aim + (size_t)j * 8192,
                s4_Cre + (size_t)j * 8192, s4_Cim + (size_t)j * 8192,
                s4_D + j * 256, GB, TkVc);
            kstate_kernel<<<dim3(4, 256), 128, 0, stream>>>(GB, uT, Sloc);
            kcross_kernel<<<dim3(4, 256), 128, 0, stream>>>(
                TkVc, uT, Sloc,
                s4_logdt + j * 256,
                s4_Alr + (size_t)j * 8192, s4_Aim + (size_t)j * 8192, yT);
            transpose_u16<<<dim3(512, 4), 256, 0, stream>>>(yT, y, D_, M_);
            gemm_kernel<0><<<dim3(M_ / 128, 2), 256, 0, stream>>>(
                y, WoutT + (size_t)j * 512 * 256, s4_bout + j * 512, x, nullptr, 256, 256);
        }
        ln_kernel<1><<<M_ / 4, 256, 0, stream>>>(x, ff_ln_w + lyr * 256, ff_ln_b + lyr * 256, ubf);
        gemm_kernel<1><<<dim3(M_ / 128, 8), 256, 0, stream>>>(
            ubf, W1T + (size_t)lyr * 1024 * 256, ff_b1 + lyr * 1024, nullptr, h, 256, 1024);
        gemm_kernel<2><<<dim3(M_ / 128, 2), 256, 0, stream>>>(
            h, W2T + (size_t)lyr * 256 * 1024, ff_b2 + lyr * 256, x, nullptr, 1024, 256);
    }

    // ---- final LN + vocab projection ----
    ln_kernel<1><<<M_ / 4, 256, 0, stream>>>(x, fin_ln_w, fin_ln_b, ubf);
    gemm_kernel<3><<<dim3(M_ / 128, 8), 256, 0, stream>>>(
        ubf, WvT, b_vocab, (float*)d_out, nullptr, 256, 1024);
}